// Round 6
// baseline (349.902 us; speedup 1.0000x reference)
//
#include <hip/hip_runtime.h>
#include <math.h>

// Problem constants (unit_gcn): N=64, C=64, T=300, V=25, S=3
//
// ws float layout:
//   [2048, 4096)   : stats, 16 replicas x (sum[64], sumsq[64])
//   [4352, 10496)  : W-frag table ushort[12288]: frag f=((s*2+kt)*4+wv), elem lane*8+j
//   [10496, 12032) : A-frag table ushort[3072]:  frag f=(s*2+nt2)
//   byte 65536+    : ypre bf16, BLOCK-CONTIGUOUS [n][bx][o][t'][w], 61.44 MB
//
// R12: R11 passed (310 us; k_main 105). WRITE-amp theory refuted (aligned
// staged stores -> WRITE went UP 127->139 MB); stop chasing it. Wall math
// across R6/R9/R11 says k_bnrelu ~= 100 us (roofline 49) + ~95 us fixed
// overhead. This round changes ONLY k_bnrelu: (n,bx)-mapped blocks read
// ypre block-contiguously (12.8 KB sequential per block, no /25 divide,
// no cross-XCD 200 B scatter); BN finalize in-block from the 16 replica
// lines (L2-hot). k_main untouched (control).

typedef __attribute__((ext_vector_type(8))) short bf16x8;
typedef __attribute__((ext_vector_type(4))) float f32x4;
typedef __attribute__((ext_vector_type(4))) ushort u16x4;
typedef __attribute__((ext_vector_type(8))) ushort u16x8;

__device__ inline ushort f2bf(float f) {
    union { float f; unsigned u; } v; v.f = f;
    unsigned r = v.u + 0x7fffu + ((v.u >> 16) & 1u);
    return (ushort)(r >> 16);
}
__device__ inline float bf2f(ushort h) {
    union { unsigned u; float f; } v; v.u = ((unsigned)h) << 16;
    return v.f;
}

// ---------------------------------------------------------------------------
// K1: 8 blocks. Normalize A (LDS), zero stats (block 0), build frag tables.
// ---------------------------------------------------------------------------
__global__ __launch_bounds__(256) void k_prep(const float* __restrict__ PA,
                                              const float* __restrict__ W,
                                              float* __restrict__ ws) {
    __shared__ float Al[1875];
    const int tid = threadIdx.x;
    const int bid = blockIdx.x;
    for (int i = tid; i < 1875; i += 256) Al[i] = PA[i];
    if (bid == 0)
        for (int i = tid; i < 2048; i += 256) ws[2048 + i] = 0.0f;
    __syncthreads();
    if (tid < 75) {
        int s = tid / 25, w = tid - s * 25;
        float ss = 0.0f;
        for (int v = 0; v < 25; ++v) {
            float p = Al[s * 625 + v * 25 + w];
            ss += p * p;
        }
        float inv = 1.0f / (sqrtf(ss) + 1e-4f);
        for (int v = 0; v < 25; ++v) Al[s * 625 + v * 25 + w] *= inv;
    }
    __syncthreads();
    int idx = bid * 256 + tid;
    if (idx < 1536) {  // W-frag: W[s][o=wv*16+col][c=kt*32+quad*8+j]
        ushort* wt = (ushort*)(ws + 4352);
        int lane = idx & 63, rest = idx >> 6;
        int wv = rest & 3, sk = rest >> 2;
        int kt = sk & 1, s = sk >> 1;
        int col = lane & 15, quad = lane >> 4;
        const float* wp = W + s * 4096 + (wv * 16 + col) * 64 + kt * 32 + quad * 8;
#pragma unroll
        for (int j = 0; j < 8; ++j) wt[idx * 8 + j] = f2bf(wp[j]);
    } else if (idx < 1920) {  // A-frag: A[s][v=quad*8+j][w=nt2*16+col], OOB->0
        ushort* at = (ushort*)(ws + 10496);
        int a = idx - 1536;
        int lane = a & 63, rest = a >> 6;
        int nt2 = rest & 1, s = rest >> 1;
        int col = lane & 15, quad = lane >> 4;
        int w = nt2 * 16 + col;
#pragma unroll
        for (int j = 0; j < 8; ++j) {
            int v = quad * 8 + j;
            float av = (v < 25 && w < 25) ? Al[s * 625 + v * 25 + w] : 0.0f;
            at[a * 8 + j] = f2bf(av);
        }
    }
}

// ---------------------------------------------------------------------------
// K2: per block one n, 4 t-steps (grid 75 x 64). UNCHANGED from R11 (control).
//  GEMM1 swapped -> Z^T lane-local in o; shfl re-layout; GEMM2; LDS-staged
//  block-contiguous ypre epilogue.
// ---------------------------------------------------------------------------
__global__ __launch_bounds__(256, 4) void k_main11(const float* __restrict__ x,
                                                   const float* __restrict__ ws,
                                                   ushort* __restrict__ ypre,
                                                   float* __restrict__ stats) {
    __shared__ __align__(16) ushort Xl[112 * 72];
    __shared__ float sst[128];

    const int tid = threadIdx.x;
    const int wv = tid >> 6;
    const int lane = tid & 63;
    const int col = lane & 15;
    const int quad = lane >> 4;
    const int strip = wv << 4;
    const int n = blockIdx.y;
    const int bx = blockIdx.x;
    const int t0 = bx * 4;

    // stage X (float4 loads): x[n, c, t0*25 + tv] -> Xl[tv*72 + c]
    {
        const float* xr = x + n * 480000 + t0 * 25;
        const int c = tid >> 2, part = tid & 3;
        const float4* row = (const float4*)(xr + c * 7500);
        for (int j = part; j < 25; j += 4) {
            float4 v4 = row[j];
            ushort* dst = &Xl[(j * 4) * 72 + c];
            dst[0]   = f2bf(v4.x);
            dst[72]  = f2bf(v4.y);
            dst[144] = f2bf(v4.z);
            dst[216] = f2bf(v4.w);
        }
        for (int i = tid; i < 864; i += 256) Xl[7200 + i] = 0;  // rows 100..111
    }
    __syncthreads();

    const ushort* wt = (const ushort*)(ws + 4352);
    const ushort* at = (const ushort*)(ws + 10496);

    // shfl source lanes for the quad re-layout (same col, quads 2q, 2q+1)
    const int s0l = col + ((quad & 1) << 5);
    const int s1l = s0l + 16;
    const bool hiq = quad >= 2;

    f32x4 yacc[4][2];
#pragma unroll
    for (int t = 0; t < 4; ++t)
#pragma unroll
        for (int j = 0; j < 2; ++j) yacc[t][j] = (f32x4){0.f, 0.f, 0.f, 0.f};

    for (int s = 0; s < 3; ++s) {
        // reload only the current-s fragments (16 live regs, L3-hot)
        bf16x8 wf0 = *(const bf16x8*)&wt[(((s * 2 + 0) * 4 + wv) * 64 + lane) * 8];
        bf16x8 wf1 = *(const bf16x8*)&wt[(((s * 2 + 1) * 4 + wv) * 64 + lane) * 8];
        bf16x8 af0 = *(const bf16x8*)&at[((s * 2 + 0) * 64 + lane) * 8];
        bf16x8 af1 = *(const bf16x8*)&at[((s * 2 + 1) * 64 + lane) * 8];
#pragma unroll
        for (int t = 0; t < 4; ++t) {
            const int r0 = (t * 25 + col) * 72 + (quad << 3);
            const int r1 = r0 + 16 * 72;
            bf16x8 x00 = *(const bf16x8*)&Xl[r0];
            bf16x8 x01 = *(const bf16x8*)&Xl[r0 + 32];
            bf16x8 x10 = *(const bf16x8*)&Xl[r1];
            bf16x8 x11 = *(const bf16x8*)&Xl[r1 + 32];
            // GEMM1 swapped: D[m=v][n=o] = X^T * W^T = Z^T  (bit-identical MACs)
            f32x4 zA = (f32x4){0.f, 0.f, 0.f, 0.f};
            f32x4 zB = (f32x4){0.f, 0.f, 0.f, 0.f};
            zA = __builtin_amdgcn_mfma_f32_16x16x32_bf16(x00, wf0, zA, 0, 0, 0);
            zA = __builtin_amdgcn_mfma_f32_16x16x32_bf16(x01, wf1, zA, 0, 0, 0);
            zB = __builtin_amdgcn_mfma_f32_16x16x32_bf16(x10, wf0, zB, 0, 0, 0);
            zB = __builtin_amdgcn_mfma_f32_16x16x32_bf16(x11, wf1, zB, 0, 0, 0);
            // pack with the bit-proven f2bf (R10's cvt_pk asm scrambled pairs)
            unsigned pa0 = (unsigned)f2bf(zA[0]) | ((unsigned)f2bf(zA[1]) << 16);
            unsigned pa1 = (unsigned)f2bf(zA[2]) | ((unsigned)f2bf(zA[3]) << 16);
            unsigned pb0 = (unsigned)f2bf(zB[0]) | ((unsigned)f2bf(zB[1]) << 16);
            unsigned pb1 = (unsigned)f2bf(zB[2]) | ((unsigned)f2bf(zB[3]) << 16);
            // quad re-layout: dest (col,q) word w: v-pairs (8q+2w, 8q+2w+1)
            unsigned ga0 = __shfl(pa0, s0l);
            unsigned ga1 = __shfl(pa1, s0l);
            unsigned ga2 = __shfl(pa0, s1l);
            unsigned ga3 = __shfl(pa1, s1l);
            unsigned gb0 = __shfl(pb0, s0l);
            unsigned gb1 = __shfl(pb1, s0l);
            unsigned gb2 = __shfl(pb0, s1l);
            unsigned gb3 = __shfl(pb1, s1l);
            union { unsigned u[4]; bf16x8 v; } zf;
            zf.u[0] = hiq ? gb0 : ga0;
            zf.u[1] = hiq ? gb1 : ga1;
            zf.u[2] = hiq ? gb2 : ga2;
            zf.u[3] = hiq ? gb3 : ga3;
            yacc[t][0] = __builtin_amdgcn_mfma_f32_16x16x32_bf16(zf.v, af0, yacc[t][0], 0, 0, 0);
            yacc[t][1] = __builtin_amdgcn_mfma_f32_16x16x32_bf16(zf.v, af1, yacc[t][1], 0, 0, 0);
        }
    }

    // ---- epilogue ----
    __syncthreads();  // all waves done reading Xl
    ushort* Ys = Xl;  // 6400 ushorts used

    float ssum[4] = {0.f, 0.f, 0.f, 0.f}, ssq[4] = {0.f, 0.f, 0.f, 0.f};
    const int obase = strip + (quad << 2);
#pragma unroll
    for (int t = 0; t < 4; ++t)
#pragma unroll
        for (int nt2 = 0; nt2 < 2; ++nt2) {
            int w = nt2 * 16 + col;
            if (w < 25) {
                f32x4 f = yacc[t][nt2];
#pragma unroll
                for (int r = 0; r < 4; ++r) {
                    float yv = f[r];
                    Ys[(obase + r) * 100 + t * 25 + w] = f2bf(yv);
                    ssum[r] += yv;
                    ssq[r] = fmaf(yv, yv, ssq[r]);
                }
            }
        }
#pragma unroll
    for (int r = 0; r < 4; ++r) {
        float a = ssum[r], b = ssq[r];
        for (int m = 1; m < 16; m <<= 1) {  // reduce over the 16 w-lanes
            a += __shfl_xor(a, m, 64);
            b += __shfl_xor(b, m, 64);
        }
        if (col == 0) {  // unique (wv,quad,r) -> unique o
            sst[obase + r] = a;
            sst[64 + obase + r] = b;
        }
    }
    __syncthreads();
    // 6400 ushorts = 800 x 16 B, fully aligned
    {
        u16x8* dst = (u16x8*)(ypre + (size_t)(n * 75 + bx) * 6400);
        const u16x8* src = (const u16x8*)Ys;
        for (int i = tid; i < 800; i += 256) dst[i] = src[i];
    }
    const int rep = (bx + blockIdx.y) & 15;
    if (tid < 128) atomicAdd(&stats[rep * 128 + tid], sst[tid]);
}

// ---------------------------------------------------------------------------
// K3: out = relu(sc[o]*bf2f(ypre) + sh[o] + x). (n,bx)-mapped: grid (75,64),
// block = one ypre chunk [n][bx][64][100] (12.8 KB sequential read, matches
// k_main's write order). x/out accessed as 64 rows x 400 B (16 full lines
// per wave-instr). BN finalize in-block from the 16 replica stats lines
// (8 KB, L2-hot). No divide. out store nontemporal (never re-read).
// ---------------------------------------------------------------------------
__global__ __launch_bounds__(256) void k_bnrelu_e(const float* __restrict__ x,
                                                  const ushort* __restrict__ ypre,
                                                  const float* __restrict__ stats,
                                                  const float* __restrict__ gamma,
                                                  const float* __restrict__ beta,
                                                  float* __restrict__ out) {
    __shared__ float tot[128];
    __shared__ float scl[64], shl[64];
    const int tid = threadIdx.x;
    const int bx = blockIdx.x;   // 0..74
    const int n = blockIdx.y;    // 0..63

    if (tid < 128) {
        float a = 0.0f;
#pragma unroll
        for (int r = 0; r < 16; ++r) a += stats[r * 128 + tid];
        tot[tid] = a;
    }
    __syncthreads();
    if (tid < 64) {
        const float invn = 1.0f / 480000.0f;  // N*T*V
        float mean = tot[tid] * invn;
        float var = tot[64 + tid] * invn - mean * mean;
        float sc = gamma[tid] * rsqrtf(var + 1e-5f);
        scl[tid] = sc;
        shl[tid] = beta[tid] - mean * sc;
    }
    __syncthreads();

    const int o = tid >> 2, part = tid & 3;
    const float sc = scl[o], sh = shl[o];
    const ushort* yb = ypre + (size_t)(n * 75 + bx) * 6400 + o * 100;
    const float* xb = x + (size_t)(n * 64 + o) * 7500 + bx * 100;
    float* ob = out + (size_t)(n * 64 + o) * 7500 + bx * 100;
#pragma unroll
    for (int j = part; j < 25; j += 4) {
        u16x4 yv = *(const u16x4*)(yb + j * 4);
        f32x4 xx = *(const f32x4*)(xb + j * 4);
        f32x4 r;
        r.x = fmaxf(fmaf(bf2f(yv.x), sc, sh) + xx.x, 0.0f);
        r.y = fmaxf(fmaf(bf2f(yv.y), sc, sh) + xx.y, 0.0f);
        r.z = fmaxf(fmaf(bf2f(yv.z), sc, sh) + xx.z, 0.0f);
        r.w = fmaxf(fmaf(bf2f(yv.w), sc, sh) + xx.w, 0.0f);
        __builtin_nontemporal_store(r, (f32x4*)(ob + j * 4));
    }
}

// ---------------------------------------------------------------------------
extern "C" void kernel_launch(void* const* d_in, const int* in_sizes, int n_in,
                              void* d_out, int out_size, void* d_ws, size_t ws_size,
                              hipStream_t stream) {
    const float* x = (const float*)d_in[0];
    const float* PA = (const float*)d_in[1];
    const float* W = (const float*)d_in[2];
    // d_in[3] = b : cancels through training-mode BN -> unused
    const float* gamma = (const float*)d_in[4];
    const float* beta = (const float*)d_in[5];
    float* wsf = (float*)d_ws;
    float* out = (float*)d_out;
    ushort* ypre = (ushort*)((char*)d_ws + 65536);

    k_prep<<<8, 256, 0, stream>>>(PA, W, wsf);
    dim3 g(75, 64);
    k_main11<<<g, 256, 0, stream>>>(x, wsf, ypre, wsf + 2048);
    dim3 gb(75, 64);
    k_bnrelu_e<<<gb, 256, 0, stream>>>(x, ypre, wsf + 2048, gamma, beta, out);
}

// Round 7
// 307.677 us; speedup vs baseline: 1.1372x; 1.1372x over previous
//
#include <hip/hip_runtime.h>
#include <math.h>

// Problem constants (unit_gcn): N=64, C=64, T=300, V=25, S=3
//
// ws float layout:
//   [2048, 4096)   : stats, 16 replicas x (sum[64], sumsq[64])
//   [4352, 10496)  : W-frag table ushort[12288]: frag f=((s*2+kt)*4+wv), elem lane*8+j
//   [10496, 12032) : A-frag table ushort[3072]:  frag f=(s*2+nt2)
//   byte 65536+    : ypre bf16, BLOCK-CONTIGUOUS [n][bx][o][t'][w], 61.44 MB
//
// R13: R12's bnrelu (n,bx) remap HURT (310->350): x/out are 246/307 MB of
// the stream and lost their coalescing; ypre pattern is irrelevant (_c ==
// _d null result). Revert bnrelu to _d. k_main: WRITE excess (27->66->78 MB
// across R6/R9/R11) tracks LIVE REGISTER growth with no FETCH growth =
// scratch-spill signature (spill dirties L2 -> HBM writeback; reload hits
// L2). VGPR_Count=64 is the arch half; with unified-file accumulators we
// sit at the (256,4)=128 cap. Measured occupancy is only ~3.2 blocks/CU
// anyway -> (256,3) (cap 168) frees ~40 regs for free. Only k_main change.

typedef __attribute__((ext_vector_type(8))) short bf16x8;
typedef __attribute__((ext_vector_type(4))) float f32x4;
typedef __attribute__((ext_vector_type(4))) ushort u16x4;
typedef __attribute__((ext_vector_type(8))) ushort u16x8;

__device__ inline ushort f2bf(float f) {
    union { float f; unsigned u; } v; v.f = f;
    unsigned r = v.u + 0x7fffu + ((v.u >> 16) & 1u);
    return (ushort)(r >> 16);
}
__device__ inline float bf2f(ushort h) {
    union { unsigned u; float f; } v; v.u = ((unsigned)h) << 16;
    return v.f;
}

// ---------------------------------------------------------------------------
// K1: 8 blocks. Normalize A (LDS), zero stats (block 0), build frag tables.
// ---------------------------------------------------------------------------
__global__ __launch_bounds__(256) void k_prep(const float* __restrict__ PA,
                                              const float* __restrict__ W,
                                              float* __restrict__ ws) {
    __shared__ float Al[1875];
    const int tid = threadIdx.x;
    const int bid = blockIdx.x;
    for (int i = tid; i < 1875; i += 256) Al[i] = PA[i];
    if (bid == 0)
        for (int i = tid; i < 2048; i += 256) ws[2048 + i] = 0.0f;
    __syncthreads();
    if (tid < 75) {
        int s = tid / 25, w = tid - s * 25;
        float ss = 0.0f;
        for (int v = 0; v < 25; ++v) {
            float p = Al[s * 625 + v * 25 + w];
            ss += p * p;
        }
        float inv = 1.0f / (sqrtf(ss) + 1e-4f);
        for (int v = 0; v < 25; ++v) Al[s * 625 + v * 25 + w] *= inv;
    }
    __syncthreads();
    int idx = bid * 256 + tid;
    if (idx < 1536) {  // W-frag: W[s][o=wv*16+col][c=kt*32+quad*8+j]
        ushort* wt = (ushort*)(ws + 4352);
        int lane = idx & 63, rest = idx >> 6;
        int wv = rest & 3, sk = rest >> 2;
        int kt = sk & 1, s = sk >> 1;
        int col = lane & 15, quad = lane >> 4;
        const float* wp = W + s * 4096 + (wv * 16 + col) * 64 + kt * 32 + quad * 8;
#pragma unroll
        for (int j = 0; j < 8; ++j) wt[idx * 8 + j] = f2bf(wp[j]);
    } else if (idx < 1920) {  // A-frag: A[s][v=quad*8+j][w=nt2*16+col], OOB->0
        ushort* at = (ushort*)(ws + 10496);
        int a = idx - 1536;
        int lane = a & 63, rest = a >> 6;
        int nt2 = rest & 1, s = rest >> 1;
        int col = lane & 15, quad = lane >> 4;
        int w = nt2 * 16 + col;
#pragma unroll
        for (int j = 0; j < 8; ++j) {
            int v = quad * 8 + j;
            float av = (v < 25 && w < 25) ? Al[s * 625 + v * 25 + w] : 0.0f;
            at[a * 8 + j] = f2bf(av);
        }
    }
}

// ---------------------------------------------------------------------------
// K2: per block one n, 4 t-steps (grid 75 x 64). Identical to R11 except
// launch_bounds (256,3): frees ~40 VGPRs (spill-theory probe); measured
// occupancy was only ~3.2 blocks/CU under (256,4) anyway.
// ---------------------------------------------------------------------------
__global__ __launch_bounds__(256, 3) void k_main13(const float* __restrict__ x,
                                                   const float* __restrict__ ws,
                                                   ushort* __restrict__ ypre,
                                                   float* __restrict__ stats) {
    __shared__ __align__(16) ushort Xl[112 * 72];
    __shared__ float sst[128];

    const int tid = threadIdx.x;
    const int wv = tid >> 6;
    const int lane = tid & 63;
    const int col = lane & 15;
    const int quad = lane >> 4;
    const int strip = wv << 4;
    const int n = blockIdx.y;
    const int bx = blockIdx.x;
    const int t0 = bx * 4;

    // stage X (float4 loads): x[n, c, t0*25 + tv] -> Xl[tv*72 + c]
    {
        const float* xr = x + n * 480000 + t0 * 25;
        const int c = tid >> 2, part = tid & 3;
        const float4* row = (const float4*)(xr + c * 7500);
        for (int j = part; j < 25; j += 4) {
            float4 v4 = row[j];
            ushort* dst = &Xl[(j * 4) * 72 + c];
            dst[0]   = f2bf(v4.x);
            dst[72]  = f2bf(v4.y);
            dst[144] = f2bf(v4.z);
            dst[216] = f2bf(v4.w);
        }
        for (int i = tid; i < 864; i += 256) Xl[7200 + i] = 0;  // rows 100..111
    }
    __syncthreads();

    const ushort* wt = (const ushort*)(ws + 4352);
    const ushort* at = (const ushort*)(ws + 10496);

    // shfl source lanes for the quad re-layout (same col, quads 2q, 2q+1)
    const int s0l = col + ((quad & 1) << 5);
    const int s1l = s0l + 16;
    const bool hiq = quad >= 2;

    f32x4 yacc[4][2];
#pragma unroll
    for (int t = 0; t < 4; ++t)
#pragma unroll
        for (int j = 0; j < 2; ++j) yacc[t][j] = (f32x4){0.f, 0.f, 0.f, 0.f};

    for (int s = 0; s < 3; ++s) {
        // reload only the current-s fragments (16 live regs, L3-hot)
        bf16x8 wf0 = *(const bf16x8*)&wt[(((s * 2 + 0) * 4 + wv) * 64 + lane) * 8];
        bf16x8 wf1 = *(const bf16x8*)&wt[(((s * 2 + 1) * 4 + wv) * 64 + lane) * 8];
        bf16x8 af0 = *(const bf16x8*)&at[((s * 2 + 0) * 64 + lane) * 8];
        bf16x8 af1 = *(const bf16x8*)&at[((s * 2 + 1) * 64 + lane) * 8];
#pragma unroll
        for (int t = 0; t < 4; ++t) {
            const int r0 = (t * 25 + col) * 72 + (quad << 3);
            const int r1 = r0 + 16 * 72;
            bf16x8 x00 = *(const bf16x8*)&Xl[r0];
            bf16x8 x01 = *(const bf16x8*)&Xl[r0 + 32];
            bf16x8 x10 = *(const bf16x8*)&Xl[r1];
            bf16x8 x11 = *(const bf16x8*)&Xl[r1 + 32];
            // GEMM1 swapped: D[m=v][n=o] = X^T * W^T = Z^T  (bit-identical MACs)
            f32x4 zA = (f32x4){0.f, 0.f, 0.f, 0.f};
            f32x4 zB = (f32x4){0.f, 0.f, 0.f, 0.f};
            zA = __builtin_amdgcn_mfma_f32_16x16x32_bf16(x00, wf0, zA, 0, 0, 0);
            zA = __builtin_amdgcn_mfma_f32_16x16x32_bf16(x01, wf1, zA, 0, 0, 0);
            zB = __builtin_amdgcn_mfma_f32_16x16x32_bf16(x10, wf0, zB, 0, 0, 0);
            zB = __builtin_amdgcn_mfma_f32_16x16x32_bf16(x11, wf1, zB, 0, 0, 0);
            // pack with the bit-proven f2bf (R10's cvt_pk asm scrambled pairs)
            unsigned pa0 = (unsigned)f2bf(zA[0]) | ((unsigned)f2bf(zA[1]) << 16);
            unsigned pa1 = (unsigned)f2bf(zA[2]) | ((unsigned)f2bf(zA[3]) << 16);
            unsigned pb0 = (unsigned)f2bf(zB[0]) | ((unsigned)f2bf(zB[1]) << 16);
            unsigned pb1 = (unsigned)f2bf(zB[2]) | ((unsigned)f2bf(zB[3]) << 16);
            // quad re-layout: dest (col,q) word w: v-pairs (8q+2w, 8q+2w+1)
            unsigned ga0 = __shfl(pa0, s0l);
            unsigned ga1 = __shfl(pa1, s0l);
            unsigned ga2 = __shfl(pa0, s1l);
            unsigned ga3 = __shfl(pa1, s1l);
            unsigned gb0 = __shfl(pb0, s0l);
            unsigned gb1 = __shfl(pb1, s0l);
            unsigned gb2 = __shfl(pb0, s1l);
            unsigned gb3 = __shfl(pb1, s1l);
            union { unsigned u[4]; bf16x8 v; } zf;
            zf.u[0] = hiq ? gb0 : ga0;
            zf.u[1] = hiq ? gb1 : ga1;
            zf.u[2] = hiq ? gb2 : ga2;
            zf.u[3] = hiq ? gb3 : ga3;
            yacc[t][0] = __builtin_amdgcn_mfma_f32_16x16x32_bf16(zf.v, af0, yacc[t][0], 0, 0, 0);
            yacc[t][1] = __builtin_amdgcn_mfma_f32_16x16x32_bf16(zf.v, af1, yacc[t][1], 0, 0, 0);
        }
    }

    // ---- epilogue ----
    __syncthreads();  // all waves done reading Xl
    ushort* Ys = Xl;  // 6400 ushorts used

    float ssum[4] = {0.f, 0.f, 0.f, 0.f}, ssq[4] = {0.f, 0.f, 0.f, 0.f};
    const int obase = strip + (quad << 2);
#pragma unroll
    for (int t = 0; t < 4; ++t)
#pragma unroll
        for (int nt2 = 0; nt2 < 2; ++nt2) {
            int w = nt2 * 16 + col;
            if (w < 25) {
                f32x4 f = yacc[t][nt2];
#pragma unroll
                for (int r = 0; r < 4; ++r) {
                    float yv = f[r];
                    Ys[(obase + r) * 100 + t * 25 + w] = f2bf(yv);
                    ssum[r] += yv;
                    ssq[r] = fmaf(yv, yv, ssq[r]);
                }
            }
        }
#pragma unroll
    for (int r = 0; r < 4; ++r) {
        float a = ssum[r], b = ssq[r];
        for (int m = 1; m < 16; m <<= 1) {  // reduce over the 16 w-lanes
            a += __shfl_xor(a, m, 64);
            b += __shfl_xor(b, m, 64);
        }
        if (col == 0) {  // unique (wv,quad,r) -> unique o
            sst[obase + r] = a;
            sst[64 + obase + r] = b;
        }
    }
    __syncthreads();
    // 6400 ushorts = 800 x 16 B, fully aligned
    {
        u16x8* dst = (u16x8*)(ypre + (size_t)(n * 75 + bx) * 6400);
        const u16x8* src = (const u16x8*)Ys;
        for (int i = tid; i < 800; i += 256) dst[i] = src[i];
    }
    const int rep = (bx + blockIdx.y) & 15;
    if (tid < 128) atomicAdd(&stats[rep * 128 + tid], sst[tid]);
}

// ---------------------------------------------------------------------------
// K3: out = relu(sc[o]*bf2f(ypre) + sh[o] + x). Plane-mapped (R5-proven _d):
// block = one (n,o) plane (4096 blocks), x/out perfectly plane-coalesced;
// ypre block-contiguous [n][bx][o][100] read in 200 B chunks (pattern shown
// irrelevant in R5/R6 A/B). BN finalize folded in; out store nontemporal.
// ---------------------------------------------------------------------------
__global__ __launch_bounds__(256) void k_bnrelu_d(const float* __restrict__ x,
                                                  const ushort* __restrict__ ypre,
                                                  const float* __restrict__ stats,
                                                  const float* __restrict__ gamma,
                                                  const float* __restrict__ beta,
                                                  float* __restrict__ out) {
    __shared__ float bsc[2];
    const int plane = blockIdx.x;  // n*64 + o
    const int o = plane & 63;
    const int n = plane >> 6;
    const int tid = threadIdx.x;
    if (tid < 16) {
        float su = stats[tid * 128 + o];
        float sq = stats[tid * 128 + 64 + o];
#pragma unroll
        for (int m = 1; m < 16; m <<= 1) {
            su += __shfl_xor(su, m, 64);
            sq += __shfl_xor(sq, m, 64);
        }
        if (tid == 0) {
            const float invn = 1.0f / 480000.0f;  // N*T*V
            float mean = su * invn;
            float var = sq * invn - mean * mean;
            float sc = gamma[o] * rsqrtf(var + 1e-5f);
            bsc[0] = sc;
            bsc[1] = beta[o] - mean * sc;
        }
    }
    __syncthreads();
    const float sc = bsc[0], sh = bsc[1];
    const ushort* ybase = ypre + (size_t)n * 480000 + o * 100;  // + bx*6400 + inner
    const f32x4* xp = (const f32x4*)(x + (size_t)plane * 7500);
    f32x4* op = (f32x4*)(out + (size_t)plane * 7500);
    for (int j4 = tid; j4 < 1875; j4 += 256) {
        int bxi = j4 / 25;            // magic-mul, j4 = bxi*25 + r4
        int r4 = j4 - bxi * 25;
        u16x4 yv = *(const u16x4*)(ybase + bxi * 6400 + r4 * 4);
        f32x4 xx = xp[j4];
        f32x4 r;
        r.x = fmaxf(fmaf(bf2f(yv.x), sc, sh) + xx.x, 0.0f);
        r.y = fmaxf(fmaf(bf2f(yv.y), sc, sh) + xx.y, 0.0f);
        r.z = fmaxf(fmaf(bf2f(yv.z), sc, sh) + xx.z, 0.0f);
        r.w = fmaxf(fmaf(bf2f(yv.w), sc, sh) + xx.w, 0.0f);
        __builtin_nontemporal_store(r, &op[j4]);
    }
}

// ---------------------------------------------------------------------------
extern "C" void kernel_launch(void* const* d_in, const int* in_sizes, int n_in,
                              void* d_out, int out_size, void* d_ws, size_t ws_size,
                              hipStream_t stream) {
    const float* x = (const float*)d_in[0];
    const float* PA = (const float*)d_in[1];
    const float* W = (const float*)d_in[2];
    // d_in[3] = b : cancels through training-mode BN -> unused
    const float* gamma = (const float*)d_in[4];
    const float* beta = (const float*)d_in[5];
    float* wsf = (float*)d_ws;
    float* out = (float*)d_out;
    ushort* ypre = (ushort*)((char*)d_ws + 65536);

    k_prep<<<8, 256, 0, stream>>>(PA, W, wsf);
    dim3 g(75, 64);
    k_main13<<<g, 256, 0, stream>>>(x, wsf, ypre, wsf + 2048);
    k_bnrelu_d<<<4096, 256, 0, stream>>>(x, ypre, wsf + 2048, gamma, beta, out);
}

// Round 8
// 297.778 us; speedup vs baseline: 1.1750x; 1.0332x over previous
//
#include <hip/hip_runtime.h>
#include <math.h>

// Problem constants (unit_gcn): N=64, C=64, T=300, V=25, S=3
//
// ws float layout:
//   [2048, 4096)   : stats, 16 replicas x (sum[64], sumsq[64])
//   [4352, 10496)  : W-frag table ushort[12288]: frag f=((s*2+kt)*4+wv), elem lane*8+j
//   [10496, 12032) : A-frag table ushort[3072]:  frag f=(s*2+nt2), K-PERMUTED (R14)
//   byte 65536+    : ypre bf16, BLOCK-CONTIGUOUS [n][bx][o][t'][w], 61.44 MB
//
// R14: R13 confirmed the spill fix by counters (WRITE 139->62.4 = ypre+stats
// exactly, VGPR 72) but dur 105->101: spill rode under a latency-bound
// kernel. Remaining chain: pack -> 8 ds_bpermute + 4 cndmask -> GEMM2, x12
// iters. Those shuffles only exist to match GEMM2's k=quad*8+j slot to
// GEMM1's D rows v=quad*4+r. k is OUR labeling: re-map k->v in the A-frag
// TABLE (v = quad*4+j for j<4, 16+quad*4+(j-4) for j>=4) so the lane-local
// pack {pa0,pa1,pb0,pb1} IS the GEMM2 A-operand. Zero shuffles. Same MFMA
// count; K-sum pairing reorder = f32 noise (threshold 0.1625, we're 0.031).

typedef __attribute__((ext_vector_type(8))) short bf16x8;
typedef __attribute__((ext_vector_type(4))) float f32x4;
typedef __attribute__((ext_vector_type(4))) ushort u16x4;
typedef __attribute__((ext_vector_type(8))) ushort u16x8;

__device__ inline ushort f2bf(float f) {
    union { float f; unsigned u; } v; v.f = f;
    unsigned r = v.u + 0x7fffu + ((v.u >> 16) & 1u);
    return (ushort)(r >> 16);
}
__device__ inline float bf2f(ushort h) {
    union { unsigned u; float f; } v; v.u = ((unsigned)h) << 16;
    return v.f;
}

// ---------------------------------------------------------------------------
// K1: 8 blocks. Normalize A (LDS), zero stats (block 0), build frag tables.
// ---------------------------------------------------------------------------
__global__ __launch_bounds__(256) void k_prep(const float* __restrict__ PA,
                                              const float* __restrict__ W,
                                              float* __restrict__ ws) {
    __shared__ float Al[1875];
    const int tid = threadIdx.x;
    const int bid = blockIdx.x;
    for (int i = tid; i < 1875; i += 256) Al[i] = PA[i];
    if (bid == 0)
        for (int i = tid; i < 2048; i += 256) ws[2048 + i] = 0.0f;
    __syncthreads();
    if (tid < 75) {
        int s = tid / 25, w = tid - s * 25;
        float ss = 0.0f;
        for (int v = 0; v < 25; ++v) {
            float p = Al[s * 625 + v * 25 + w];
            ss += p * p;
        }
        float inv = 1.0f / (sqrtf(ss) + 1e-4f);
        for (int v = 0; v < 25; ++v) Al[s * 625 + v * 25 + w] *= inv;
    }
    __syncthreads();
    int idx = bid * 256 + tid;
    if (idx < 1536) {  // W-frag: W[s][o=wv*16+col][c=kt*32+quad*8+j]
        ushort* wt = (ushort*)(ws + 4352);
        int lane = idx & 63, rest = idx >> 6;
        int wv = rest & 3, sk = rest >> 2;
        int kt = sk & 1, s = sk >> 1;
        int col = lane & 15, quad = lane >> 4;
        const float* wp = W + s * 4096 + (wv * 16 + col) * 64 + kt * 32 + quad * 8;
#pragma unroll
        for (int j = 0; j < 8; ++j) wt[idx * 8 + j] = f2bf(wp[j]);
    } else if (idx < 1920) {  // A-frag, K-PERMUTED: k=quad*8+j -> v below
        ushort* at = (ushort*)(ws + 10496);
        int a = idx - 1536;
        int lane = a & 63, rest = a >> 6;
        int nt2 = rest & 1, s = rest >> 1;
        int col = lane & 15, quad = lane >> 4;
        int w = nt2 * 16 + col;
#pragma unroll
        for (int j = 0; j < 8; ++j) {
            // j<4: v = quad*4+j (zA rows); j>=4: v = 16+quad*4+(j-4) (zB rows)
            int v = quad * 4 + (j < 4 ? j : j + 12);
            float av = (v < 25 && w < 25) ? Al[s * 625 + v * 25 + w] : 0.0f;
            at[a * 8 + j] = f2bf(av);
        }
    }
}

// ---------------------------------------------------------------------------
// K2: per block one n, 4 t-steps (grid 75 x 64).
//  GEMM1 (per s,t), operands swapped: zA/zB = mfma(x_frag, w_frag) gives
//    Z^T[v][o]: o = strip+col (lane-local), v = quad*4+r (+16 for zB).
//  GEMM2: the K-permuted A-frag table makes {pa0,pa1,pb0,pb1} directly the
//    A-operand — NO shfl, NO cndmask (R14). yacc[t] += zf * A_s.
//  Epilogue: LDS-stage 64x100 tile (overlay Xl) -> block-contiguous ypre.
// LDS: Xl [112 rows][72] bf16 (16.1 KB). launch_bounds (256,3): no spill
// (R13-proven: WRITE == ypre+stats exactly).
// ---------------------------------------------------------------------------
__global__ __launch_bounds__(256, 3) void k_main14(const float* __restrict__ x,
                                                   const float* __restrict__ ws,
                                                   ushort* __restrict__ ypre,
                                                   float* __restrict__ stats) {
    __shared__ __align__(16) ushort Xl[112 * 72];
    __shared__ float sst[128];

    const int tid = threadIdx.x;
    const int wv = tid >> 6;
    const int lane = tid & 63;
    const int col = lane & 15;
    const int quad = lane >> 4;
    const int strip = wv << 4;
    const int n = blockIdx.y;
    const int bx = blockIdx.x;
    const int t0 = bx * 4;

    // stage X (float4 loads): x[n, c, t0*25 + tv] -> Xl[tv*72 + c]
    {
        const float* xr = x + n * 480000 + t0 * 25;
        const int c = tid >> 2, part = tid & 3;
        const float4* row = (const float4*)(xr + c * 7500);
        for (int j = part; j < 25; j += 4) {
            float4 v4 = row[j];
            ushort* dst = &Xl[(j * 4) * 72 + c];
            dst[0]   = f2bf(v4.x);
            dst[72]  = f2bf(v4.y);
            dst[144] = f2bf(v4.z);
            dst[216] = f2bf(v4.w);
        }
        for (int i = tid; i < 864; i += 256) Xl[7200 + i] = 0;  // rows 100..111
    }
    __syncthreads();

    const ushort* wt = (const ushort*)(ws + 4352);
    const ushort* at = (const ushort*)(ws + 10496);

    f32x4 yacc[4][2];
#pragma unroll
    for (int t = 0; t < 4; ++t)
#pragma unroll
        for (int j = 0; j < 2; ++j) yacc[t][j] = (f32x4){0.f, 0.f, 0.f, 0.f};

    for (int s = 0; s < 3; ++s) {
        // reload only the current-s fragments (16 live regs, L3-hot)
        bf16x8 wf0 = *(const bf16x8*)&wt[(((s * 2 + 0) * 4 + wv) * 64 + lane) * 8];
        bf16x8 wf1 = *(const bf16x8*)&wt[(((s * 2 + 1) * 4 + wv) * 64 + lane) * 8];
        bf16x8 af0 = *(const bf16x8*)&at[((s * 2 + 0) * 64 + lane) * 8];
        bf16x8 af1 = *(const bf16x8*)&at[((s * 2 + 1) * 64 + lane) * 8];
#pragma unroll
        for (int t = 0; t < 4; ++t) {
            const int r0 = (t * 25 + col) * 72 + (quad << 3);
            const int r1 = r0 + 16 * 72;
            bf16x8 x00 = *(const bf16x8*)&Xl[r0];
            bf16x8 x01 = *(const bf16x8*)&Xl[r0 + 32];
            bf16x8 x10 = *(const bf16x8*)&Xl[r1];
            bf16x8 x11 = *(const bf16x8*)&Xl[r1 + 32];
            // GEMM1 swapped: D[m=v][n=o] = X^T * W^T = Z^T  (bit-identical MACs)
            f32x4 zA = (f32x4){0.f, 0.f, 0.f, 0.f};
            f32x4 zB = (f32x4){0.f, 0.f, 0.f, 0.f};
            zA = __builtin_amdgcn_mfma_f32_16x16x32_bf16(x00, wf0, zA, 0, 0, 0);
            zA = __builtin_amdgcn_mfma_f32_16x16x32_bf16(x01, wf1, zA, 0, 0, 0);
            zB = __builtin_amdgcn_mfma_f32_16x16x32_bf16(x10, wf0, zB, 0, 0, 0);
            zB = __builtin_amdgcn_mfma_f32_16x16x32_bf16(x11, wf1, zB, 0, 0, 0);
            // lane-local pack IS the GEMM2 A-operand (K-permuted table)
            union { unsigned u[4]; bf16x8 v; } zf;
            zf.u[0] = (unsigned)f2bf(zA[0]) | ((unsigned)f2bf(zA[1]) << 16);
            zf.u[1] = (unsigned)f2bf(zA[2]) | ((unsigned)f2bf(zA[3]) << 16);
            zf.u[2] = (unsigned)f2bf(zB[0]) | ((unsigned)f2bf(zB[1]) << 16);
            zf.u[3] = (unsigned)f2bf(zB[2]) | ((unsigned)f2bf(zB[3]) << 16);
            yacc[t][0] = __builtin_amdgcn_mfma_f32_16x16x32_bf16(zf.v, af0, yacc[t][0], 0, 0, 0);
            yacc[t][1] = __builtin_amdgcn_mfma_f32_16x16x32_bf16(zf.v, af1, yacc[t][1], 0, 0, 0);
        }
    }

    // ---- epilogue ----
    __syncthreads();  // all waves done reading Xl
    ushort* Ys = Xl;  // 6400 ushorts used

    float ssum[4] = {0.f, 0.f, 0.f, 0.f}, ssq[4] = {0.f, 0.f, 0.f, 0.f};
    const int obase = strip + (quad << 2);
#pragma unroll
    for (int t = 0; t < 4; ++t)
#pragma unroll
        for (int nt2 = 0; nt2 < 2; ++nt2) {
            int w = nt2 * 16 + col;
            if (w < 25) {
                f32x4 f = yacc[t][nt2];
#pragma unroll
                for (int r = 0; r < 4; ++r) {
                    float yv = f[r];
                    Ys[(obase + r) * 100 + t * 25 + w] = f2bf(yv);
                    ssum[r] += yv;
                    ssq[r] = fmaf(yv, yv, ssq[r]);
                }
            }
        }
#pragma unroll
    for (int r = 0; r < 4; ++r) {
        float a = ssum[r], b = ssq[r];
        for (int m = 1; m < 16; m <<= 1) {  // reduce over the 16 w-lanes
            a += __shfl_xor(a, m, 64);
            b += __shfl_xor(b, m, 64);
        }
        if (col == 0) {  // unique (wv,quad,r) -> unique o
            sst[obase + r] = a;
            sst[64 + obase + r] = b;
        }
    }
    __syncthreads();
    // 6400 ushorts = 800 x 16 B, fully aligned
    {
        u16x8* dst = (u16x8*)(ypre + (size_t)(n * 75 + bx) * 6400);
        const u16x8* src = (const u16x8*)Ys;
        for (int i = tid; i < 800; i += 256) dst[i] = src[i];
    }
    const int rep = (bx + blockIdx.y) & 15;
    if (tid < 128) atomicAdd(&stats[rep * 128 + tid], sst[tid]);
}

// ---------------------------------------------------------------------------
// K3: out = relu(sc[o]*bf2f(ypre) + sh[o] + x). Plane-mapped (R5-proven _d):
// block = one (n,o) plane (4096 blocks), x/out perfectly plane-coalesced;
// ypre read pattern shown irrelevant (R5/R6 A/B). BN finalize folded in;
// out store nontemporal.
// ---------------------------------------------------------------------------
__global__ __launch_bounds__(256) void k_bnrelu_d(const float* __restrict__ x,
                                                  const ushort* __restrict__ ypre,
                                                  const float* __restrict__ stats,
                                                  const float* __restrict__ gamma,
                                                  const float* __restrict__ beta,
                                                  float* __restrict__ out) {
    __shared__ float bsc[2];
    const int plane = blockIdx.x;  // n*64 + o
    const int o = plane & 63;
    const int n = plane >> 6;
    const int tid = threadIdx.x;
    if (tid < 16) {
        float su = stats[tid * 128 + o];
        float sq = stats[tid * 128 + 64 + o];
#pragma unroll
        for (int m = 1; m < 16; m <<= 1) {
            su += __shfl_xor(su, m, 64);
            sq += __shfl_xor(sq, m, 64);
        }
        if (tid == 0) {
            const float invn = 1.0f / 480000.0f;  // N*T*V
            float mean = su * invn;
            float var = sq * invn - mean * mean;
            float sc = gamma[o] * rsqrtf(var + 1e-5f);
            bsc[0] = sc;
            bsc[1] = beta[o] - mean * sc;
        }
    }
    __syncthreads();
    const float sc = bsc[0], sh = bsc[1];
    const ushort* ybase = ypre + (size_t)n * 480000 + o * 100;  // + bx*6400 + inner
    const f32x4* xp = (const f32x4*)(x + (size_t)plane * 7500);
    f32x4* op = (f32x4*)(out + (size_t)plane * 7500);
    for (int j4 = tid; j4 < 1875; j4 += 256) {
        int bxi = j4 / 25;            // magic-mul, j4 = bxi*25 + r4
        int r4 = j4 - bxi * 25;
        u16x4 yv = *(const u16x4*)(ybase + bxi * 6400 + r4 * 4);
        f32x4 xx = xp[j4];
        f32x4 r;
        r.x = fmaxf(fmaf(bf2f(yv.x), sc, sh) + xx.x, 0.0f);
        r.y = fmaxf(fmaf(bf2f(yv.y), sc, sh) + xx.y, 0.0f);
        r.z = fmaxf(fmaf(bf2f(yv.z), sc, sh) + xx.z, 0.0f);
        r.w = fmaxf(fmaf(bf2f(yv.w), sc, sh) + xx.w, 0.0f);
        __builtin_nontemporal_store(r, &op[j4]);
    }
}

// ---------------------------------------------------------------------------
extern "C" void kernel_launch(void* const* d_in, const int* in_sizes, int n_in,
                              void* d_out, int out_size, void* d_ws, size_t ws_size,
                              hipStream_t stream) {
    const float* x = (const float*)d_in[0];
    const float* PA = (const float*)d_in[1];
    const float* W = (const float*)d_in[2];
    // d_in[3] = b : cancels through training-mode BN -> unused
    const float* gamma = (const float*)d_in[4];
    const float* beta = (const float*)d_in[5];
    float* wsf = (float*)d_ws;
    float* out = (float*)d_out;
    ushort* ypre = (ushort*)((char*)d_ws + 65536);

    k_prep<<<8, 256, 0, stream>>>(PA, W, wsf);
    dim3 g(75, 64);
    k_main14<<<g, 256, 0, stream>>>(x, wsf, ypre, wsf + 2048);
    k_bnrelu_d<<<4096, 256, 0, stream>>>(x, ypre, wsf + 2048, gamma, beta, out);
}

// Round 9
// 292.203 us; speedup vs baseline: 1.1975x; 1.0191x over previous
//
#include <hip/hip_runtime.h>
#include <math.h>

// Problem constants (unit_gcn): N=64, C=64, T=300, V=25, S=3
//
// ws float layout:
//   [2048, 4096)   : stats, 16 replicas x (sum[64], sumsq[64])
//   [4352, 10496)  : W-frag table ushort[12288]: frag f=((s*2+kt)*4+wv), elem lane*8+j
//   [10496, 12032) : A-frag table ushort[3072]:  frag f=(s*2+nt2), K-PERMUTED (R14)
//   byte 65536+    : ypre bf16, BLOCK-CONTIGUOUS [n][bx][o][t'][w], 61.44 MB
//
// R15: R14 killed the shuffles (bank-conflict 6.1M->2.5M, 101->92.5) but
// k_main is still latency-bound (MfmaUtil 9.6, VALU 22.6, HBM 19, all idle;
// 143 MB of traffic would stream in ~35 us). Remaining gate: per-s frag
// reload (4 global loads, L3-hot ~200+ cy) serializes each s-phase's 12
// MFMAs. We now sit at VGPR 72 under the (256,3)=168 cap -> hoist all 12
// frags (48 regs) + full s-unroll: loads issue once, overlap X-staging,
// compiler pipelines the 3 s-phases. Spill canary: WRITE must stay 62.4 MB.

typedef __attribute__((ext_vector_type(8))) short bf16x8;
typedef __attribute__((ext_vector_type(4))) float f32x4;
typedef __attribute__((ext_vector_type(4))) ushort u16x4;
typedef __attribute__((ext_vector_type(8))) ushort u16x8;

__device__ inline ushort f2bf(float f) {
    union { float f; unsigned u; } v; v.f = f;
    unsigned r = v.u + 0x7fffu + ((v.u >> 16) & 1u);
    return (ushort)(r >> 16);
}
__device__ inline float bf2f(ushort h) {
    union { unsigned u; float f; } v; v.u = ((unsigned)h) << 16;
    return v.f;
}

// ---------------------------------------------------------------------------
// K1: 8 blocks. Normalize A (LDS), zero stats (block 0), build frag tables.
// ---------------------------------------------------------------------------
__global__ __launch_bounds__(256) void k_prep(const float* __restrict__ PA,
                                              const float* __restrict__ W,
                                              float* __restrict__ ws) {
    __shared__ float Al[1875];
    const int tid = threadIdx.x;
    const int bid = blockIdx.x;
    for (int i = tid; i < 1875; i += 256) Al[i] = PA[i];
    if (bid == 0)
        for (int i = tid; i < 2048; i += 256) ws[2048 + i] = 0.0f;
    __syncthreads();
    if (tid < 75) {
        int s = tid / 25, w = tid - s * 25;
        float ss = 0.0f;
        for (int v = 0; v < 25; ++v) {
            float p = Al[s * 625 + v * 25 + w];
            ss += p * p;
        }
        float inv = 1.0f / (sqrtf(ss) + 1e-4f);
        for (int v = 0; v < 25; ++v) Al[s * 625 + v * 25 + w] *= inv;
    }
    __syncthreads();
    int idx = bid * 256 + tid;
    if (idx < 1536) {  // W-frag: W[s][o=wv*16+col][c=kt*32+quad*8+j]
        ushort* wt = (ushort*)(ws + 4352);
        int lane = idx & 63, rest = idx >> 6;
        int wv = rest & 3, sk = rest >> 2;
        int kt = sk & 1, s = sk >> 1;
        int col = lane & 15, quad = lane >> 4;
        const float* wp = W + s * 4096 + (wv * 16 + col) * 64 + kt * 32 + quad * 8;
#pragma unroll
        for (int j = 0; j < 8; ++j) wt[idx * 8 + j] = f2bf(wp[j]);
    } else if (idx < 1920) {  // A-frag, K-PERMUTED: k=quad*8+j -> v below
        ushort* at = (ushort*)(ws + 10496);
        int a = idx - 1536;
        int lane = a & 63, rest = a >> 6;
        int nt2 = rest & 1, s = rest >> 1;
        int col = lane & 15, quad = lane >> 4;
        int w = nt2 * 16 + col;
#pragma unroll
        for (int j = 0; j < 8; ++j) {
            // j<4: v = quad*4+j (zA rows); j>=4: v = 16+quad*4+(j-4) (zB rows)
            int v = quad * 4 + (j < 4 ? j : j + 12);
            float av = (v < 25 && w < 25) ? Al[s * 625 + v * 25 + w] : 0.0f;
            at[a * 8 + j] = f2bf(av);
        }
    }
}

// ---------------------------------------------------------------------------
// K2: per block one n, 4 t-steps (grid 75 x 64).
//  All 12 fragments hoisted to registers (48 regs, fits (256,3)=168 cap);
//  s-loop fully unrolled -> frag loads issue once, overlap X-staging.
//  GEMM1 swapped: zA/zB = mfma(x_frag, w_frag) -> Z^T, o lane-local.
//  GEMM2: K-permuted A-frag table makes the lane-local pack the A-operand
//  directly (no shuffles). Epilogue: LDS-staged block-contiguous ypre.
// ---------------------------------------------------------------------------
__global__ __launch_bounds__(256, 3) void k_main15(const float* __restrict__ x,
                                                   const float* __restrict__ ws,
                                                   ushort* __restrict__ ypre,
                                                   float* __restrict__ stats) {
    __shared__ __align__(16) ushort Xl[112 * 72];
    __shared__ float sst[128];

    const int tid = threadIdx.x;
    const int wv = tid >> 6;
    const int lane = tid & 63;
    const int col = lane & 15;
    const int quad = lane >> 4;
    const int strip = wv << 4;
    const int n = blockIdx.y;
    const int bx = blockIdx.x;
    const int t0 = bx * 4;

    const ushort* wt = (const ushort*)(ws + 4352);
    const ushort* at = (const ushort*)(ws + 10496);

    // hoist all 12 fragments (issued before staging; L3-hot)
    bf16x8 wf[6], af[6];
#pragma unroll
    for (int s = 0; s < 3; ++s) {
        wf[s * 2 + 0] = *(const bf16x8*)&wt[(((s * 2 + 0) * 4 + wv) * 64 + lane) * 8];
        wf[s * 2 + 1] = *(const bf16x8*)&wt[(((s * 2 + 1) * 4 + wv) * 64 + lane) * 8];
        af[s * 2 + 0] = *(const bf16x8*)&at[((s * 2 + 0) * 64 + lane) * 8];
        af[s * 2 + 1] = *(const bf16x8*)&at[((s * 2 + 1) * 64 + lane) * 8];
    }

    // stage X (float4 loads): x[n, c, t0*25 + tv] -> Xl[tv*72 + c]
    {
        const float* xr = x + n * 480000 + t0 * 25;
        const int c = tid >> 2, part = tid & 3;
        const float4* row = (const float4*)(xr + c * 7500);
        for (int j = part; j < 25; j += 4) {
            float4 v4 = row[j];
            ushort* dst = &Xl[(j * 4) * 72 + c];
            dst[0]   = f2bf(v4.x);
            dst[72]  = f2bf(v4.y);
            dst[144] = f2bf(v4.z);
            dst[216] = f2bf(v4.w);
        }
        for (int i = tid; i < 864; i += 256) Xl[7200 + i] = 0;  // rows 100..111
    }
    __syncthreads();

    f32x4 yacc[4][2];
#pragma unroll
    for (int t = 0; t < 4; ++t)
#pragma unroll
        for (int j = 0; j < 2; ++j) yacc[t][j] = (f32x4){0.f, 0.f, 0.f, 0.f};

#pragma unroll
    for (int s = 0; s < 3; ++s) {
#pragma unroll
        for (int t = 0; t < 4; ++t) {
            const int r0 = (t * 25 + col) * 72 + (quad << 3);
            const int r1 = r0 + 16 * 72;
            bf16x8 x00 = *(const bf16x8*)&Xl[r0];
            bf16x8 x01 = *(const bf16x8*)&Xl[r0 + 32];
            bf16x8 x10 = *(const bf16x8*)&Xl[r1];
            bf16x8 x11 = *(const bf16x8*)&Xl[r1 + 32];
            // GEMM1 swapped: D[m=v][n=o] = X^T * W^T = Z^T  (bit-identical MACs)
            f32x4 zA = (f32x4){0.f, 0.f, 0.f, 0.f};
            f32x4 zB = (f32x4){0.f, 0.f, 0.f, 0.f};
            zA = __builtin_amdgcn_mfma_f32_16x16x32_bf16(x00, wf[s * 2 + 0], zA, 0, 0, 0);
            zA = __builtin_amdgcn_mfma_f32_16x16x32_bf16(x01, wf[s * 2 + 1], zA, 0, 0, 0);
            zB = __builtin_amdgcn_mfma_f32_16x16x32_bf16(x10, wf[s * 2 + 0], zB, 0, 0, 0);
            zB = __builtin_amdgcn_mfma_f32_16x16x32_bf16(x11, wf[s * 2 + 1], zB, 0, 0, 0);
            // lane-local pack IS the GEMM2 A-operand (K-permuted table)
            union { unsigned u[4]; bf16x8 v; } zf;
            zf.u[0] = (unsigned)f2bf(zA[0]) | ((unsigned)f2bf(zA[1]) << 16);
            zf.u[1] = (unsigned)f2bf(zA[2]) | ((unsigned)f2bf(zA[3]) << 16);
            zf.u[2] = (unsigned)f2bf(zB[0]) | ((unsigned)f2bf(zB[1]) << 16);
            zf.u[3] = (unsigned)f2bf(zB[2]) | ((unsigned)f2bf(zB[3]) << 16);
            yacc[t][0] = __builtin_amdgcn_mfma_f32_16x16x32_bf16(zf.v, af[s * 2 + 0], yacc[t][0], 0, 0, 0);
            yacc[t][1] = __builtin_amdgcn_mfma_f32_16x16x32_bf16(zf.v, af[s * 2 + 1], yacc[t][1], 0, 0, 0);
        }
    }

    // ---- epilogue ----
    __syncthreads();  // all waves done reading Xl
    ushort* Ys = Xl;  // 6400 ushorts used

    float ssum[4] = {0.f, 0.f, 0.f, 0.f}, ssq[4] = {0.f, 0.f, 0.f, 0.f};
    const int obase = strip + (quad << 2);
#pragma unroll
    for (int t = 0; t < 4; ++t)
#pragma unroll
        for (int nt2 = 0; nt2 < 2; ++nt2) {
            int w = nt2 * 16 + col;
            if (w < 25) {
                f32x4 f = yacc[t][nt2];
#pragma unroll
                for (int r = 0; r < 4; ++r) {
                    float yv = f[r];
                    Ys[(obase + r) * 100 + t * 25 + w] = f2bf(yv);
                    ssum[r] += yv;
                    ssq[r] = fmaf(yv, yv, ssq[r]);
                }
            }
        }
#pragma unroll
    for (int r = 0; r < 4; ++r) {
        float a = ssum[r], b = ssq[r];
        for (int m = 1; m < 16; m <<= 1) {  // reduce over the 16 w-lanes
            a += __shfl_xor(a, m, 64);
            b += __shfl_xor(b, m, 64);
        }
        if (col == 0) {  // unique (wv,quad,r) -> unique o
            sst[obase + r] = a;
            sst[64 + obase + r] = b;
        }
    }
    __syncthreads();
    // 6400 ushorts = 800 x 16 B, fully aligned
    {
        u16x8* dst = (u16x8*)(ypre + (size_t)(n * 75 + bx) * 6400);
        const u16x8* src = (const u16x8*)Ys;
        for (int i = tid; i < 800; i += 256) dst[i] = src[i];
    }
    const int rep = (bx + blockIdx.y) & 15;
    if (tid < 128) atomicAdd(&stats[rep * 128 + tid], sst[tid]);
}

// ---------------------------------------------------------------------------
// K3: out = relu(sc[o]*bf2f(ypre) + sh[o] + x). Plane-mapped (R5-proven _d):
// block = one (n,o) plane (4096 blocks), x/out perfectly plane-coalesced;
// ypre read pattern shown irrelevant (R5/R6 A/B). BN finalize folded in;
// out store nontemporal. UNCHANGED (control).
// ---------------------------------------------------------------------------
__global__ __launch_bounds__(256) void k_bnrelu_d(const float* __restrict__ x,
                                                  const ushort* __restrict__ ypre,
                                                  const float* __restrict__ stats,
                                                  const float* __restrict__ gamma,
                                                  const float* __restrict__ beta,
                                                  float* __restrict__ out) {
    __shared__ float bsc[2];
    const int plane = blockIdx.x;  // n*64 + o
    const int o = plane & 63;
    const int n = plane >> 6;
    const int tid = threadIdx.x;
    if (tid < 16) {
        float su = stats[tid * 128 + o];
        float sq = stats[tid * 128 + 64 + o];
#pragma unroll
        for (int m = 1; m < 16; m <<= 1) {
            su += __shfl_xor(su, m, 64);
            sq += __shfl_xor(sq, m, 64);
        }
        if (tid == 0) {
            const float invn = 1.0f / 480000.0f;  // N*T*V
            float mean = su * invn;
            float var = sq * invn - mean * mean;
            float sc = gamma[o] * rsqrtf(var + 1e-5f);
            bsc[0] = sc;
            bsc[1] = beta[o] - mean * sc;
        }
    }
    __syncthreads();
    const float sc = bsc[0], sh = bsc[1];
    const ushort* ybase = ypre + (size_t)n * 480000 + o * 100;  // + bx*6400 + inner
    const f32x4* xp = (const f32x4*)(x + (size_t)plane * 7500);
    f32x4* op = (f32x4*)(out + (size_t)plane * 7500);
    for (int j4 = tid; j4 < 1875; j4 += 256) {
        int bxi = j4 / 25;            // magic-mul, j4 = bxi*25 + r4
        int r4 = j4 - bxi * 25;
        u16x4 yv = *(const u16x4*)(ybase + bxi * 6400 + r4 * 4);
        f32x4 xx = xp[j4];
        f32x4 r;
        r.x = fmaxf(fmaf(bf2f(yv.x), sc, sh) + xx.x, 0.0f);
        r.y = fmaxf(fmaf(bf2f(yv.y), sc, sh) + xx.y, 0.0f);
        r.z = fmaxf(fmaf(bf2f(yv.z), sc, sh) + xx.z, 0.0f);
        r.w = fmaxf(fmaf(bf2f(yv.w), sc, sh) + xx.w, 0.0f);
        __builtin_nontemporal_store(r, &op[j4]);
    }
}

// ---------------------------------------------------------------------------
extern "C" void kernel_launch(void* const* d_in, const int* in_sizes, int n_in,
                              void* d_out, int out_size, void* d_ws, size_t ws_size,
                              hipStream_t stream) {
    const float* x = (const float*)d_in[0];
    const float* PA = (const float*)d_in[1];
    const float* W = (const float*)d_in[2];
    // d_in[3] = b : cancels through training-mode BN -> unused
    const float* gamma = (const float*)d_in[4];
    const float* beta = (const float*)d_in[5];
    float* wsf = (float*)d_ws;
    float* out = (float*)d_out;
    ushort* ypre = (ushort*)((char*)d_ws + 65536);

    k_prep<<<8, 256, 0, stream>>>(PA, W, wsf);
    dim3 g(75, 64);
    k_main15<<<g, 256, 0, stream>>>(x, wsf, ypre, wsf + 2048);
    k_bnrelu_d<<<4096, 256, 0, stream>>>(x, ypre, wsf + 2048, gamma, beta, out);
}